// Round 9
// baseline (146.248 us; speedup 1.0000x reference)
//
#include <hip/hip_runtime.h>
#include <math.h>

#define NPTS 65536
#define DIM 64
#define NCODE 1024

typedef float f32x2 __attribute__((ext_vector_type(2)));
typedef float f32x4 __attribute__((ext_vector_type(4)));
typedef short bf16x8 __attribute__((ext_vector_type(8)));
typedef unsigned short u16x4 __attribute__((ext_vector_type(4)));

// output layout (flat float32 concat, reference return order)
#define OFF_LOSS 0ull
#define OFF_Q    1ull
#define OFF_PERP 4194305ull
#define OFF_ENC  4194306ull
#define OFF_IDX  71303170ull

// Scratch stashed INSIDE the one-hot output region (cached d_out; d_ws bulk
// reads are uncached per r5/r6 evidence). Overwritten by vq_stream afterwards.
// +2 floats makes the base 16B-aligned (OFF_ENC%4==2).
#define STASH (OFF_ENC + 2)

__device__ __forceinline__ unsigned short bf16hi(float f) {
    unsigned u = __float_as_uint(f);
    unsigned r = u + 0x7FFFu + ((u >> 16) & 1u);   // RNE truncate to bf16
    return (unsigned short)(r >> 16);
}
__device__ __forceinline__ float bf16tof(unsigned short h) {
    return __uint_as_float(((unsigned)h) << 16);
}

// 8 consecutive fp32 (16B-aligned) -> hi/lo bf16x8
__device__ __forceinline__ void cvt8(const float* p, bf16x8& hi, bf16x8& lo) {
    float4 a = *(const float4*)p;
    float4 b = *(const float4*)(p + 4);
    float v[8] = {a.x, a.y, a.z, a.w, b.x, b.y, b.z, b.w};
#pragma unroll
    for (int i = 0; i < 8; ++i) {
        unsigned short h = bf16hi(v[i]);
        hi[i] = (short)h;
        lo[i] = (short)bf16hi(v[i] - bf16tof(h));
    }
}

// ---------------- prep: emb -> bf16 hi/lo split + ||e||^2, stashed in d_out ----------------
__global__ __launch_bounds__(256) void vq_prep(const float* __restrict__ emb,
                                               float* __restrict__ out) {
    const int k = blockIdx.x * 256 + threadIdx.x;          // code 0..1023
    unsigned short* ehi = (unsigned short*)(out + STASH);
    unsigned short* elo = ehi + NCODE * DIM;
    float* e2 = (float*)(elo + NCODE * DIM);

    const float4* ep = (const float4*)(emb + (size_t)k * DIM);
    float s = 0.f;
#pragma unroll
    for (int q = 0; q < 16; ++q) {
        float4 v = ep[q];
        float vv[4] = {v.x, v.y, v.z, v.w};
        u16x4 hi, lo;
#pragma unroll
        for (int i = 0; i < 4; ++i) {
            s = fmaf(vv[i], vv[i], s);
            unsigned short hb = bf16hi(vv[i]);
            hi[i] = hb;
            lo[i] = bf16hi(vv[i] - bf16tof(hb));
        }
        *(u16x4*)(ehi + (size_t)k * DIM + q * 4) = hi;
        *(u16x4*)(elo + (size_t)k * DIM + q * 4) = lo;
    }
    e2[k] = s;
}

// ---------------- distance argmin via bf16-split MFMA ----------------
// Block = 4 waves, 64 points. fp32 x tile in LDS; A-frags (all 4 pt-tiles)
// built once via register cvt. Wave wv scans codes [256wv,256wv+256).
// B hi/lo + e2 read pre-split from the d_out stash (L2-resident, 260KB).
// dist = e2 - 2*(xh.eh + xh.el + xl.eh). Packed-u64 (sortable dist, code)
// argmin = exact first-min tie-break. idx sink = out[OFF_IDX] (cached).
__global__ __launch_bounds__(256, 4) void vq_dist(const float* __restrict__ in,
                                                  float* __restrict__ out,
                                                  unsigned int* __restrict__ hist) {
    __shared__ __align__(16) float lds_x[64][68];
    __shared__ unsigned long long cand[4][64];

    const int tid  = threadIdx.x;
    const int lane = tid & 63;
    const int wv   = __builtin_amdgcn_readfirstlane(tid >> 6);

    const unsigned short* ehi = (const unsigned short*)(out + STASH);
    const unsigned short* elo = ehi + NCODE * DIM;
    const float* e2 = (const float*)(elo + NCODE * DIM);

    const int P0 = blockIdx.x * 64;
    const int b  = P0 >> 12;
    const int h  = (P0 >> 6) & 63;
    const float* base = in + (size_t)b * (DIM * 4096) + h * 64;

    // prologue: 64x64 fp32 tile, coalesced load, transpose into LDS
    {
        int d  = tid >> 2;
        int wq = tid & 3;
        const float* rowp = base + (size_t)d * 4096 + wq * 16;
#pragma unroll
        for (int j = 0; j < 4; ++j) {
            float4 v = *(const float4*)(rowp + j * 4);
            int w0 = wq * 16 + j * 4;
            lds_x[w0 + 0][d] = v.x;
            lds_x[w0 + 1][d] = v.y;
            lds_x[w0 + 2][d] = v.z;
            lds_x[w0 + 3][d] = v.w;
        }
    }
    __syncthreads();

    const int m15 = lane & 15;
    const int g4  = lane >> 4;
    const int kb  = g4 * 8;            // this lane's k-slice base
    const int c0w = wv * 256;          // this wave's code slice (ascending)

    // A fragments, all 4 point-tiles resident (A row = lane&15, k = kb..)
    bf16x8 Ahi[4][2], Alo[4][2];
#pragma unroll
    for (int pt = 0; pt < 4; ++pt) {
        int p = pt * 16 + m15;
        cvt8(&lds_x[p][kb],      Ahi[pt][0], Alo[pt][0]);
        cvt8(&lds_x[p][kb + 32], Ahi[pt][1], Alo[pt][1]);
    }

    float best[4][4];
    int   bestk[4][4];
#pragma unroll
    for (int pt = 0; pt < 4; ++pt)
#pragma unroll
        for (int r = 0; r < 4; ++r) { best[pt][r] = INFINITY; bestk[pt][r] = 0; }

    for (int ct = 0; ct < 16; ++ct) {
        const int code = c0w + ct * 16 + m15;          // B col = lane&15
        const unsigned short* eh = ehi + (size_t)code * DIM + kb;
        const unsigned short* el = elo + (size_t)code * DIM + kb;
        bf16x8 Bhi0 = *(const bf16x8*)eh;
        bf16x8 Bhi1 = *(const bf16x8*)(eh + 32);
        bf16x8 Blo0 = *(const bf16x8*)el;
        bf16x8 Blo1 = *(const bf16x8*)(el + 32);
        const float e2v = e2[code];

#pragma unroll
        for (int pt = 0; pt < 4; ++pt) {
            f32x4 acc = {0.f, 0.f, 0.f, 0.f};
            acc = __builtin_amdgcn_mfma_f32_16x16x32_bf16(Ahi[pt][0], Bhi0, acc, 0, 0, 0);
            acc = __builtin_amdgcn_mfma_f32_16x16x32_bf16(Ahi[pt][1], Bhi1, acc, 0, 0, 0);
            acc = __builtin_amdgcn_mfma_f32_16x16x32_bf16(Ahi[pt][0], Blo0, acc, 0, 0, 0);
            acc = __builtin_amdgcn_mfma_f32_16x16x32_bf16(Ahi[pt][1], Blo1, acc, 0, 0, 0);
            acc = __builtin_amdgcn_mfma_f32_16x16x32_bf16(Alo[pt][0], Bhi0, acc, 0, 0, 0);
            acc = __builtin_amdgcn_mfma_f32_16x16x32_bf16(Alo[pt][1], Bhi1, acc, 0, 0, 0);
#pragma unroll
            for (int r = 0; r < 4; ++r) {
                float dist = fmaf(-2.0f, acc[r], e2v);
                if (dist < best[pt][r]) { best[pt][r] = dist; bestk[pt][r] = code; }
            }
        }
    }

    // per-wave cross-lane argmin over 16 cols, lexicographic (dist, code)
#pragma unroll
    for (int pt = 0; pt < 4; ++pt) {
#pragma unroll
        for (int r = 0; r < 4; ++r) {
            unsigned u = __float_as_uint(best[pt][r]);
            u = (u & 0x80000000u) ? ~u : (u | 0x80000000u);   // monotone f32->u32
            unsigned long long key = ((unsigned long long)u << 32) | (unsigned)bestk[pt][r];
#pragma unroll
            for (int sm = 1; sm < 16; sm <<= 1) {
                unsigned long long o = __shfl_xor(key, sm, 16);
                key = (o < key) ? o : key;
            }
            if (m15 == 0) cand[wv][pt * 16 + g4 * 4 + r] = key;
        }
    }
    __syncthreads();

    if (tid < 64) {   // merge 4 wave-slices (ascending -> first-min tie-break)
        unsigned long long k0 = cand[0][tid];
#pragma unroll
        for (int s = 1; s < 4; ++s) {
            unsigned long long o = cand[s][tid];
            if (o < k0) k0 = o;
        }
        int idx = (int)(k0 & 0xFFFFFFFFull);
        out[OFF_IDX + P0 + tid] = (float)idx;      // sole idx sink (cached d_out)
        atomicAdd(&hist[idx], 1u);
    }
}

// ---------------- stream: q_ste + loss + one-hot (idx read from d_out) ----------------
__global__ __launch_bounds__(256) void vq_stream(const float* __restrict__ in,
                                                 const float* __restrict__ emb,
                                                 float* __restrict__ out,
                                                 float* __restrict__ loss_acc) {
    __shared__ int s_idx[64];
    const int tid = threadIdx.x;
    const int P0  = blockIdx.x * 64;
    if (tid < 64) s_idx[tid] = (int)out[OFF_IDX + P0 + tid];   // exact for 0..1023
    __syncthreads();

    const int b  = P0 >> 12;
    const int h  = (P0 >> 6) & 63;
    const int w  = tid & 63;
    const int dg = tid >> 6;                       // wave id = d-group
    {
        const int myidx = s_idx[w];
        const float* eq = emb + (size_t)myidx * DIM + dg * 16;
        const float* xb = in + ((size_t)b * 64 + dg * 16) * 4096 + h * 64 + w;
        float* qb = out + OFF_Q + ((size_t)b * 64 + dg * 16) * 4096 + h * 64 + w;

        float lsum = 0.f;
#pragma unroll
        for (int dd = 0; dd < 16; ++dd) {
            float x = xb[(size_t)dd * 4096];
            float diff = eq[dd] - x;
            lsum = fmaf(diff, diff, lsum);
            qb[(size_t)dd * 4096] = x + diff;      // exact STE form; plain store
        }
        for (int off = 32; off > 0; off >>= 1) lsum += __shfl_down(lsum, off, 64);
        if ((tid & 63) == 0) atomicAdd(loss_acc, lsum);
    }

    // one-hot: wave wv owns rows [16wv, 16wv+16); per row each lane stores
    // 4x f32x4 -> 1024B/wave-instruction, nontemporal (no L2 pollution).
    {
        const int wv = tid >> 6;
        const int lane = tid & 63;
        f32x4* enc4 = (f32x4*)(out + OFF_ENC + (unsigned long long)P0 * NCODE);
#pragma unroll
        for (int rr = 0; rr < 16; ++rr) {
            const int row = wv * 16 + rr;          // wave-uniform
            const int target = s_idx[row];
#pragma unroll
            for (int k = 0; k < 4; ++k) {
                const int j = k * 64 + lane;       // f32x4 index in row
                const int c0 = j * 4;
                f32x4 v;
                v.x = (c0 + 0 == target) ? 1.0f : 0.0f;
                v.y = (c0 + 1 == target) ? 1.0f : 0.0f;
                v.z = (c0 + 2 == target) ? 1.0f : 0.0f;
                v.w = (c0 + 3 == target) ? 1.0f : 0.0f;
                __builtin_nontemporal_store(v, &enc4[(size_t)row * 256 + j]);
            }
        }
    }
}

// ---------------- finalize: loss scalar + perplexity ----------------
__global__ __launch_bounds__(1024) void vq_finalize(const unsigned int* __restrict__ hist,
                                                    const float* __restrict__ loss_acc,
                                                    float* __restrict__ out) {
    int t = threadIdx.x;
    float c = (float)hist[t];
    float pv = c * (1.0f / (float)NPTS);
    float term = pv * logf(pv + 1e-10f);

    __shared__ float red[16];
    float s = term;
    for (int off = 32; off > 0; off >>= 1) s += __shfl_down(s, off, 64);
    if ((t & 63) == 0) red[t >> 6] = s;
    __syncthreads();
    if (t < 16) {
        float v = red[t];
        for (int off = 8; off > 0; off >>= 1) v += __shfl_down(v, off, 64);
        if (t == 0) {
            out[OFF_PERP] = expf(-v);
            out[OFF_LOSS] = 0.25f * loss_acc[0] * (1.0f / 4194304.0f);
        }
    }
}

extern "C" void kernel_launch(void* const* d_in, const int* in_sizes, int n_in,
                              void* d_out, int out_size, void* d_ws, size_t ws_size,
                              hipStream_t stream) {
    const float* in  = (const float*)d_in[0];   // (16,64,64,64) BCHW
    const float* emb = (const float*)d_in[1];   // (1024,64)
    float* out = (float*)d_out;

    // ws: [0..15] loss_acc f32 | [16..1039] hist u32  (atomics only; no bulk)
    float* ws_f = (float*)d_ws;
    float* loss_acc = ws_f;
    unsigned int* hist = (unsigned int*)d_ws + 16;

    (void)hipMemsetAsync(d_ws, 0, (16 + NCODE) * sizeof(float), stream);

    vq_prep<<<NCODE / 256, 256, 0, stream>>>(emb, out);
    vq_dist<<<NPTS / 64, 256, 0, stream>>>(in, out, hist);
    vq_stream<<<NPTS / 64, 256, 0, stream>>>(in, emb, out, loss_acc);
    vq_finalize<<<1, 1024, 0, stream>>>(hist, loss_acc, out);
}

// Round 10
// 105.379 us; speedup vs baseline: 1.3878x; 1.3878x over previous
//
#include <hip/hip_runtime.h>
#include <math.h>

#define NPTS 65536
#define DIM 64
#define NCODE 1024

typedef float f32x2 __attribute__((ext_vector_type(2)));
typedef float f32x4 __attribute__((ext_vector_type(4)));
typedef short bf16x8 __attribute__((ext_vector_type(8)));

// output layout (flat float32 concat, reference return order)
#define OFF_LOSS 0ull
#define OFF_Q    1ull
#define OFF_PERP 4194305ull
#define OFF_ENC  4194306ull
#define OFF_IDX  71303170ull

__device__ __forceinline__ unsigned short bf16hi(float f) {
    unsigned u = __float_as_uint(f);
    unsigned r = u + 0x7FFFu + ((u >> 16) & 1u);   // RNE truncate to bf16
    return (unsigned short)(r >> 16);
}
__device__ __forceinline__ float bf16tof(unsigned short h) {
    return __uint_as_float(((unsigned)h) << 16);
}

// 8 consecutive fp32 (16B-aligned) -> hi/lo bf16x8
__device__ __forceinline__ void cvt8(const float* p, bf16x8& hi, bf16x8& lo) {
    float4 a = *(const float4*)p;
    float4 b = *(const float4*)(p + 4);
    float v[8] = {a.x, a.y, a.z, a.w, b.x, b.y, b.z, b.w};
#pragma unroll
    for (int i = 0; i < 8; ++i) {
        unsigned short h = bf16hi(v[i]);
        hi[i] = (short)h;
        lo[i] = (short)bf16hi(v[i] - bf16tof(h));
    }
}
__device__ __forceinline__ void cvt8v(float4 a, float4 b, bf16x8& hi, bf16x8& lo) {
    float v[8] = {a.x, a.y, a.z, a.w, b.x, b.y, b.z, b.w};
#pragma unroll
    for (int i = 0; i < 8; ++i) {
        unsigned short h = bf16hi(v[i]);
        hi[i] = (short)h;
        lo[i] = (short)bf16hi(v[i] - bf16tof(h));
    }
}

// ---------------- fused: MFMA argmin + q_ste + loss + one-hot ----------------
// Block = 4 waves, 64 points (one b,h w-row).
//  1) x tile fp32 -> LDS (transposed), A-frags via register cvt (all 4 pt).
//  2) wave wv scans codes [256wv,256wv+256): B inline-cvt from emb (d_in ->
//     L2-cached; d_ws bulk is uncached, r5/r6), e2 via shfl_xor; 24 MFMA/ct.
//     dist = e2 - 2*(xh.eh + xh.el + xl.eh); packed-u64 argmin (exact
//     first-min tie-break).
//  3) epilogue (idx in LDS, x from LDS): q_ste plain stores + loss atomic;
//     one-hot 1024B/wave NT f32x4 stores (r8-proven patterns).
__global__ __launch_bounds__(256, 3) void vq_fused(const float* __restrict__ in,
                                                   const float* __restrict__ emb,
                                                   float* __restrict__ out,
                                                   unsigned int* __restrict__ hist,
                                                   float* __restrict__ loss_acc) {
    __shared__ __align__(16) float lds_x[64][68];
    __shared__ unsigned long long cand[4][64];
    __shared__ int s_idx[64];

    const int tid  = threadIdx.x;
    const int lane = tid & 63;
    const int wv   = __builtin_amdgcn_readfirstlane(tid >> 6);

    const int P0 = blockIdx.x * 64;
    const int b  = P0 >> 12;
    const int h  = (P0 >> 6) & 63;
    const float* base = in + (size_t)b * (DIM * 4096) + h * 64;

    // ---- stage x: 64x64 fp32 tile, coalesced load, transpose into LDS ----
    {
        int d  = tid >> 2;
        int wq = tid & 3;
        const float* rowp = base + (size_t)d * 4096 + wq * 16;
#pragma unroll
        for (int j = 0; j < 4; ++j) {
            float4 v = *(const float4*)(rowp + j * 4);
            int w0 = wq * 16 + j * 4;
            lds_x[w0 + 0][d] = v.x;
            lds_x[w0 + 1][d] = v.y;
            lds_x[w0 + 2][d] = v.z;
            lds_x[w0 + 3][d] = v.w;
        }
    }
    __syncthreads();

    const int m15 = lane & 15;
    const int g4  = lane >> 4;
    const int kb  = g4 * 8;            // this lane's k-slice base (8 fp32)
    const int c0w = wv * 256;          // this wave's code slice (ascending)

    // A fragments, all 4 point-tiles resident (A row = lane&15, k = kb..)
    bf16x8 Ahi[4][2], Alo[4][2];
#pragma unroll
    for (int pt = 0; pt < 4; ++pt) {
        int p = pt * 16 + m15;
        cvt8(&lds_x[p][kb],      Ahi[pt][0], Alo[pt][0]);
        cvt8(&lds_x[p][kb + 32], Ahi[pt][1], Alo[pt][1]);
    }

    float best[4][4];
    int   bestk[4][4];
#pragma unroll
    for (int pt = 0; pt < 4; ++pt)
#pragma unroll
        for (int r = 0; r < 4; ++r) { best[pt][r] = INFINITY; bestk[pt][r] = 0; }

    for (int ct = 0; ct < 16; ++ct) {
        const int code = c0w + ct * 16 + m15;          // B col = lane&15
        const float* ep = emb + (size_t)code * DIM + kb;
        float4 e0 = *(const float4*)ep;
        float4 e1 = *(const float4*)(ep + 4);
        float4 e2a = *(const float4*)(ep + 32);
        float4 e3 = *(const float4*)(ep + 36);

        // ||e||^2: 16 local squares, then sum the 4 k-slices (xor keeps m15)
        float sq = e0.x * e0.x;
        sq = fmaf(e0.y, e0.y, sq); sq = fmaf(e0.z, e0.z, sq); sq = fmaf(e0.w, e0.w, sq);
        sq = fmaf(e1.x, e1.x, sq); sq = fmaf(e1.y, e1.y, sq); sq = fmaf(e1.z, e1.z, sq); sq = fmaf(e1.w, e1.w, sq);
        sq = fmaf(e2a.x, e2a.x, sq); sq = fmaf(e2a.y, e2a.y, sq); sq = fmaf(e2a.z, e2a.z, sq); sq = fmaf(e2a.w, e2a.w, sq);
        sq = fmaf(e3.x, e3.x, sq); sq = fmaf(e3.y, e3.y, sq); sq = fmaf(e3.z, e3.z, sq); sq = fmaf(e3.w, e3.w, sq);
        sq += __shfl_xor(sq, 16, 64);
        sq += __shfl_xor(sq, 32, 64);
        const float e2v = sq;

        bf16x8 Bhi0, Blo0, Bhi1, Blo1;
        cvt8v(e0, e1, Bhi0, Blo0);
        cvt8v(e2a, e3, Bhi1, Blo1);

#pragma unroll
        for (int pt = 0; pt < 4; ++pt) {
            f32x4 acc = {0.f, 0.f, 0.f, 0.f};
            acc = __builtin_amdgcn_mfma_f32_16x16x32_bf16(Ahi[pt][0], Bhi0, acc, 0, 0, 0);
            acc = __builtin_amdgcn_mfma_f32_16x16x32_bf16(Ahi[pt][1], Bhi1, acc, 0, 0, 0);
            acc = __builtin_amdgcn_mfma_f32_16x16x32_bf16(Ahi[pt][0], Blo0, acc, 0, 0, 0);
            acc = __builtin_amdgcn_mfma_f32_16x16x32_bf16(Ahi[pt][1], Blo1, acc, 0, 0, 0);
            acc = __builtin_amdgcn_mfma_f32_16x16x32_bf16(Alo[pt][0], Bhi0, acc, 0, 0, 0);
            acc = __builtin_amdgcn_mfma_f32_16x16x32_bf16(Alo[pt][1], Bhi1, acc, 0, 0, 0);
#pragma unroll
            for (int r = 0; r < 4; ++r) {
                float dist = fmaf(-2.0f, acc[r], e2v);
                if (dist < best[pt][r]) { best[pt][r] = dist; bestk[pt][r] = code; }
            }
        }
    }

    // per-wave cross-lane argmin over 16 cols, lexicographic (dist, code)
#pragma unroll
    for (int pt = 0; pt < 4; ++pt) {
#pragma unroll
        for (int r = 0; r < 4; ++r) {
            unsigned u = __float_as_uint(best[pt][r]);
            u = (u & 0x80000000u) ? ~u : (u | 0x80000000u);   // monotone f32->u32
            unsigned long long key = ((unsigned long long)u << 32) | (unsigned)bestk[pt][r];
#pragma unroll
            for (int sm = 1; sm < 16; sm <<= 1) {
                unsigned long long o = __shfl_xor(key, sm, 16);
                key = (o < key) ? o : key;
            }
            if (m15 == 0) cand[wv][pt * 16 + g4 * 4 + r] = key;
        }
    }
    __syncthreads();

    if (tid < 64) {   // merge 4 wave-slices (ascending -> first-min tie-break)
        unsigned long long k0 = cand[0][tid];
#pragma unroll
        for (int s = 1; s < 4; ++s) {
            unsigned long long o = cand[s][tid];
            if (o < k0) k0 = o;
        }
        int idx = (int)(k0 & 0xFFFFFFFFull);
        s_idx[tid] = idx;
        out[OFF_IDX + P0 + tid] = (float)idx;
        atomicAdd(&hist[idx], 1u);
    }
    __syncthreads();

    // ---- q_ste + loss: wave wv owns dims [16wv,16wv+16); x from LDS ----
    {
        const int w = lane;
        const int myidx = s_idx[w];
        const float* eq = emb + (size_t)myidx * DIM + wv * 16;
        float* qb = out + OFF_Q + ((size_t)b * 64 + wv * 16) * 4096 + h * 64 + w;
        float lsum = 0.f;
#pragma unroll
        for (int dd = 0; dd < 16; ++dd) {
            float x = lds_x[w][wv * 16 + dd];
            float diff = eq[dd] - x;
            lsum = fmaf(diff, diff, lsum);
            qb[(size_t)dd * 4096] = x + diff;      // exact STE form; plain store
        }
        for (int off = 32; off > 0; off >>= 1) lsum += __shfl_down(lsum, off, 64);
        if (lane == 0) atomicAdd(loss_acc, lsum);
    }

    // ---- one-hot: wave wv owns rows [16wv,16wv+16); 1024B/wave NT stores ----
    {
        f32x4* enc4 = (f32x4*)(out + OFF_ENC + (unsigned long long)P0 * NCODE);
#pragma unroll
        for (int rr = 0; rr < 16; ++rr) {
            const int row = wv * 16 + rr;          // wave-uniform
            const int target = s_idx[row];
#pragma unroll
            for (int k = 0; k < 4; ++k) {
                const int j = k * 64 + lane;       // f32x4 index in row
                const int c0 = j * 4;
                f32x4 v;
                v.x = (c0 + 0 == target) ? 1.0f : 0.0f;
                v.y = (c0 + 1 == target) ? 1.0f : 0.0f;
                v.z = (c0 + 2 == target) ? 1.0f : 0.0f;
                v.w = (c0 + 3 == target) ? 1.0f : 0.0f;
                __builtin_nontemporal_store(v, &enc4[(size_t)row * 256 + j]);
            }
        }
    }
}

// ---------------- finalize: loss scalar + perplexity ----------------
__global__ __launch_bounds__(1024) void vq_finalize(const unsigned int* __restrict__ hist,
                                                    const float* __restrict__ loss_acc,
                                                    float* __restrict__ out) {
    int t = threadIdx.x;
    float c = (float)hist[t];
    float pv = c * (1.0f / (float)NPTS);
    float term = pv * logf(pv + 1e-10f);

    __shared__ float red[16];
    float s = term;
    for (int off = 32; off > 0; off >>= 1) s += __shfl_down(s, off, 64);
    if ((t & 63) == 0) red[t >> 6] = s;
    __syncthreads();
    if (t < 16) {
        float v = red[t];
        for (int off = 8; off > 0; off >>= 1) v += __shfl_down(v, off, 64);
        if (t == 0) {
            out[OFF_PERP] = expf(-v);
            out[OFF_LOSS] = 0.25f * loss_acc[0] * (1.0f / 4194304.0f);
        }
    }
}

extern "C" void kernel_launch(void* const* d_in, const int* in_sizes, int n_in,
                              void* d_out, int out_size, void* d_ws, size_t ws_size,
                              hipStream_t stream) {
    const float* in  = (const float*)d_in[0];   // (16,64,64,64) BCHW
    const float* emb = (const float*)d_in[1];   // (1024,64)
    float* out = (float*)d_out;

    // ws: [0..15] loss_acc f32 | [16..1039] hist u32  (atomics only; no bulk)
    float* ws_f = (float*)d_ws;
    float* loss_acc = ws_f;
    unsigned int* hist = (unsigned int*)d_ws + 16;

    (void)hipMemsetAsync(d_ws, 0, (16 + NCODE) * sizeof(float), stream);

    vq_fused<<<NPTS / 64, 256, 0, stream>>>(in, emb, out, hist, loss_acc);
    vq_finalize<<<1, 1024, 0, stream>>>(hist, loss_acc, out);
}